// Round 6
// baseline (72.419 us; speedup 1.0000x reference)
//
#include <hip/hip_runtime.h>
#include <hip/hip_bf16.h>

// PerspectiveTransformLayer: B=4, H=64, W=64, C=128, N=10 transforms.
// out[b,y,x,c] = sum_n mask[b,n,y,x] * warp_nearest(image[b], t[b,n])[y,x,c] / count
// count = sum_n mask[b,n,y,x] (0 if count==0).
//
// R6: lanes-per-pixel 16 -> 8 (each lane owns 16 floats = four float4
// gathers). Halves wave count again (4096 -> 2048): phase-1 homography
// VALU (incl. 20 f32 div sequences) is per-wave-redundant, and R5 showed
// it scales ~linearly with wave count (73.3 -> 70.0 us). Gathers stay
// coalesced: 8 lanes x 64B = 512B contiguous per pixel-group; 20 loads in
// flight per half-batch of 5 transforms.
// Kept: XCD-bijective swizzle, LDS transform table (exact pow2 rescale),
// branch-free two-phase loop, single 1/count normalize, NT stores.

namespace {

typedef float f32x4 __attribute__((ext_vector_type(4)));

constexpr int Bc = 4;
constexpr int Hc = 64;
constexpr int Wc = 64;
constexpr int Cc = 128;
constexpr int Nc = 10;
constexpr int C4 = Cc / 4;           // 32 float4 per pixel
constexpr int LANES_PER_PIX = 8;     // each lane owns 4 float4 (16 floats)
constexpr int PIX_PER_BLOCK = 256 / LANES_PER_PIX;  // 32
constexpr int NXCD = 8;

__global__ __launch_bounds__(256)
void perspective_warp_avg_kernel(const float* __restrict__ image,
                                 const float* __restrict__ transforms,
                                 const float* __restrict__ mask,
                                 float* __restrict__ out) {
    // --- XCD-aware swizzle (bijective: gridDim.x = 512 = 8*64) ---
    const int nblk = gridDim.x;                 // 512
    const int chunk = nblk / NXCD;              // 64
    const int bid = (int)blockIdx.x;
    const int wg = (bid & (NXCD - 1)) * chunk + (bid >> 3);

    const int tid = threadIdx.x;
    const int pixInBlock = tid >> 3;            // 0..31
    const int c16 = tid & 7;                    // 16-float slot within channels
    const int pixel = wg * PIX_PER_BLOCK + pixInBlock;
    const int b  = pixel >> 12;                 // / 4096
    const int yx = pixel & 4095;
    const int y  = yx >> 6;
    const int x  = yx & 63;

    // Transforms for this batch -> LDS, pre-divided by perspective_mul.
    // mul = {1,1,4, 1,1,4, .25,.25}; /4 == *0.25f and /0.25 == *4.0f exactly.
    __shared__ float t_s[Nc * 8];
    if (tid < Nc * 8) {
        const int j = tid & 7;
        const float m = (j == 2 || j == 5) ? 0.25f : ((j >= 6) ? 4.0f : 1.0f);
        t_s[tid] = transforms[b * (Nc * 8) + tid] * m;
    }
    __syncthreads();

    const float fx = (float)x;
    const float fy = (float)y;
    const f32x4* __restrict__ imgb =
        (const f32x4*)(image) + (size_t)b * (Hc * Wc * C4);
    const float* __restrict__ maskb = mask + (size_t)(b * Nc) * (Hc * Wc) + y * Wc + x;

    // ---- Phase 1: per-transform address + weight (branch-free) ----
    int   off[Nc];   // first float4 offset into imgb for this lane
    float w[Nc];     // mask if valid else 0
    float count = 0.f;

#pragma unroll
    for (int n = 0; n < Nc; ++n) {
        const float t0 = t_s[n * 8 + 0];
        const float t1 = t_s[n * 8 + 1];
        const float t2 = t_s[n * 8 + 2];
        const float t3 = t_s[n * 8 + 3];
        const float t4 = t_s[n * 8 + 4];
        const float t5 = t_s[n * 8 + 5];
        const float t6 = t_s[n * 8 + 6];
        const float t7 = t_s[n * 8 + 7];

        const float denom = t6 * fx + t7 * fy + 1.0f;
        // exact f32 divides: these feed the floor(x+0.5) pixel decision
        const float xin = (t0 * fx + t1 * fy + t2) / denom;
        const float yin = (t3 * fx + t4 * fy + t5) / denom;

        const bool valid = (xin >= 0.0f) & (xin <= (float)(Wc - 1)) &
                           (yin >= 0.0f) & (yin <= (float)(Hc - 1));

        int xi = (int)floorf(xin + 0.5f);   // round half-up
        int yi = (int)floorf(yin + 0.5f);
        xi = min(max(xi, 0), Wc - 1);
        yi = min(max(yi, 0), Hc - 1);

        const float m = maskb[n * (Hc * Wc)];
        count += m;
        w[n]   = valid ? m : 0.0f;              // image finite -> 0*s == 0
        off[n] = (yi * Wc + xi) * C4 + c16 * 4;
    }

    // ---- Phase 2: gathers in two half-batches (20 loads in flight each) ----
    f32x4 a0 = (f32x4)(0.f);
    f32x4 a1 = (f32x4)(0.f);
    f32x4 a2 = (f32x4)(0.f);
    f32x4 a3 = (f32x4)(0.f);
#pragma unroll
    for (int h = 0; h < 2; ++h) {
        f32x4 s0[5], s1[5], s2[5], s3[5];
#pragma unroll
        for (int k = 0; k < 5; ++k) {
            const int n = h * 5 + k;
            s0[k] = imgb[off[n] + 0];
            s1[k] = imgb[off[n] + 1];
            s2[k] = imgb[off[n] + 2];
            s3[k] = imgb[off[n] + 3];
        }
#pragma unroll
        for (int k = 0; k < 5; ++k) {
            const int n = h * 5 + k;
            a0 += w[n] * s0[k];
            a1 += w[n] * s1[k];
            a2 += w[n] * s2[k];
            a3 += w[n] * s3[k];
        }
    }

    // Final normalize: one exact divide, then multiply (<=1ulp vs per-elem
    // divide; no decision boundary downstream). count==0 -> acc==0 -> out 0.
    const float inv = (count > 0.f) ? (1.0f / count) : 0.0f;

    f32x4* outp = ((f32x4*)out) + (size_t)pixel * C4 + c16 * 4;
    __builtin_nontemporal_store(a0 * inv, outp + 0);
    __builtin_nontemporal_store(a1 * inv, outp + 1);
    __builtin_nontemporal_store(a2 * inv, outp + 2);
    __builtin_nontemporal_store(a3 * inv, outp + 3);
}

}  // namespace

extern "C" void kernel_launch(void* const* d_in, const int* in_sizes, int n_in,
                              void* d_out, int out_size, void* d_ws, size_t ws_size,
                              hipStream_t stream) {
    const float* image      = (const float*)d_in[0];  // (4,64,64,128) f32
    const float* transforms = (const float*)d_in[1];  // (4,10,8) f32
    const float* mask       = (const float*)d_in[2];  // (4,10,64,64) f32
    float* out              = (float*)d_out;          // (4,64,64,128) f32

    const int totalPixels = Bc * Hc * Wc;             // 16384
    const int grid = totalPixels / PIX_PER_BLOCK;     // 512 blocks
    perspective_warp_avg_kernel<<<grid, 256, 0, stream>>>(image, transforms, mask, out);
}

// Round 7
// 67.866 us; speedup vs baseline: 1.0671x; 1.0671x over previous
//
#include <hip/hip_runtime.h>
#include <hip/hip_bf16.h>

// PerspectiveTransformLayer: B=4, H=64, W=64, C=128, N=10 transforms.
// out[b,y,x,c] = sum_n mask[b,n,y,x] * warp_nearest(image[b], t[b,n])[y,x,c] / count
// count = sum_n mask[b,n,y,x] (0 if count==0).
//
// R7: revert to R5's wave shape (16 lanes/pixel, 1024 blocks, 4096 waves —
// R6 showed fewer waves loses more latency-hiding than it saves VALU), and
// de-duplicate phase-1 instead: the (base_offset, w, m) triple is identical
// across a pixel's 16 lanes, so one thread per (pixel, transform) pair
// (160 of 256 threads) computes it once into LDS; everyone then reads the
// 10 triples back via broadcast ds_read_b128 (conflict-free). Phase-1
// wave-time drops ~10x without touching wave count.
// Kept: XCD-bijective swizzle, LDS transform table (exact pow2 rescale),
// branch-free gathers with 10 loads in flight, single 1/count normalize,
// NT stores.

namespace {

typedef float f32x4 __attribute__((ext_vector_type(4)));

constexpr int Bc = 4;
constexpr int Hc = 64;
constexpr int Wc = 64;
constexpr int Cc = 128;
constexpr int Nc = 10;
constexpr int C4 = Cc / 4;           // 32 float4 per pixel
constexpr int LANES_PER_PIX = 16;    // each lane owns 2 float4 (8 floats)
constexpr int PIX_PER_BLOCK = 256 / LANES_PER_PIX;  // 16
constexpr int NXCD = 8;

__global__ __launch_bounds__(256)
void perspective_warp_avg_kernel(const float* __restrict__ image,
                                 const float* __restrict__ transforms,
                                 const float* __restrict__ mask,
                                 float* __restrict__ out) {
    // --- XCD-aware swizzle (bijective: gridDim.x = 1024 = 8*128) ---
    const int nblk = gridDim.x;                 // 1024
    const int chunk = nblk / NXCD;              // 128
    const int bid = (int)blockIdx.x;
    const int wg = (bid & (NXCD - 1)) * chunk + (bid >> 3);

    const int tid = threadIdx.x;
    const int pixel0 = wg * PIX_PER_BLOCK;      // 16 consecutive pixels; 16|4096
    const int b = pixel0 >> 12;                 // batch is uniform per block

    // Transforms for this batch -> LDS, pre-divided by perspective_mul.
    // mul = {1,1,4, 1,1,4, .25,.25}; /4 == *0.25f and /0.25 == *4.0f exactly.
    __shared__ float t_s[Nc * 8];
    if (tid < Nc * 8) {
        const int j = tid & 7;
        const float m = (j == 2 || j == 5) ? 0.25f : ((j >= 6) ? 4.0f : 1.0f);
        t_s[tid] = transforms[b * (Nc * 8) + tid] * m;
    }
    __syncthreads();

    // ---- Phase 1 (deduplicated): one thread per (pixel, transform) ----
    // pw[p][n] = { as_float(base_f4_offset), w, m, unused }
    __shared__ f32x4 pw[PIX_PER_BLOCK][Nc];
    if (tid < PIX_PER_BLOCK * Nc) {             // 160 threads
        const int p = tid / Nc;                 // 0..15 (magic-mul div)
        const int n = tid - p * Nc;             // 0..9
        const int pix = pixel0 + p;
        const int yx = pix & 4095;
        const float fy = (float)(yx >> 6);
        const float fx = (float)(yx & 63);

        const float t0 = t_s[n * 8 + 0];
        const float t1 = t_s[n * 8 + 1];
        const float t2 = t_s[n * 8 + 2];
        const float t3 = t_s[n * 8 + 3];
        const float t4 = t_s[n * 8 + 4];
        const float t5 = t_s[n * 8 + 5];
        const float t6 = t_s[n * 8 + 6];
        const float t7 = t_s[n * 8 + 7];

        const float denom = t6 * fx + t7 * fy + 1.0f;
        // exact f32 divides: these feed the floor(x+0.5) pixel decision
        const float xin = (t0 * fx + t1 * fy + t2) / denom;
        const float yin = (t3 * fx + t4 * fy + t5) / denom;

        const bool valid = (xin >= 0.0f) & (xin <= (float)(Wc - 1)) &
                           (yin >= 0.0f) & (yin <= (float)(Hc - 1));

        int xi = (int)floorf(xin + 0.5f);       // round half-up
        int yi = (int)floorf(yin + 0.5f);
        xi = min(max(xi, 0), Wc - 1);
        yi = min(max(yi, 0), Hc - 1);

        const float m = mask[(size_t)(b * Nc + n) * (Hc * Wc) + yx];
        const int base = (yi * Wc + xi) * C4;   // float4 offset, lane-invariant

        f32x4 rec;
        rec.x = __int_as_float(base);
        rec.y = valid ? m : 0.0f;               // w (image finite -> 0*s == 0)
        rec.z = m;                              // for count
        rec.w = 0.0f;
        pw[p][n] = rec;
    }
    __syncthreads();

    // ---- Phase 2: per-thread gathers (R5 structure) ----
    const int pixInBlock = tid >> 4;            // 0..15
    const int c8 = tid & 15;                    // 8-float slot within channels
    const int pixel = pixel0 + pixInBlock;

    const f32x4* __restrict__ imgb =
        (const f32x4*)(image) + (size_t)b * (Hc * Wc * C4);

    int   off[Nc];
    float w[Nc];
    float count = 0.f;
#pragma unroll
    for (int n = 0; n < Nc; ++n) {
        const f32x4 rec = pw[pixInBlock][n];    // broadcast read (same addr
        off[n] = __float_as_int(rec.x) + c8 * 2; //  across the 16-lane group)
        w[n]   = rec.y;
        count += rec.z;
    }

    f32x4 a0 = (f32x4)(0.f);
    f32x4 a1 = (f32x4)(0.f);
#pragma unroll
    for (int h = 0; h < 2; ++h) {
        f32x4 s0[5], s1[5];
#pragma unroll
        for (int k = 0; k < 5; ++k) {
            const int n = h * 5 + k;
            s0[k] = imgb[off[n]];
            s1[k] = imgb[off[n] + 1];
        }
#pragma unroll
        for (int k = 0; k < 5; ++k) {
            const int n = h * 5 + k;
            a0 += w[n] * s0[k];
            a1 += w[n] * s1[k];
        }
    }

    // Final normalize: one exact divide, then multiply (<=1ulp vs per-elem
    // divide; no decision boundary downstream). count==0 -> acc==0 -> out 0.
    const float inv = (count > 0.f) ? (1.0f / count) : 0.0f;
    const f32x4 o0 = a0 * inv;
    const f32x4 o1 = a1 * inv;

    f32x4* outp = ((f32x4*)out) + (size_t)pixel * C4 + c8 * 2;
    __builtin_nontemporal_store(o0, outp);
    __builtin_nontemporal_store(o1, outp + 1);
}

}  // namespace

extern "C" void kernel_launch(void* const* d_in, const int* in_sizes, int n_in,
                              void* d_out, int out_size, void* d_ws, size_t ws_size,
                              hipStream_t stream) {
    const float* image      = (const float*)d_in[0];  // (4,64,64,128) f32
    const float* transforms = (const float*)d_in[1];  // (4,10,8) f32
    const float* mask       = (const float*)d_in[2];  // (4,10,64,64) f32
    float* out              = (float*)d_out;          // (4,64,64,128) f32

    const int totalPixels = Bc * Hc * Wc;             // 16384
    const int grid = totalPixels / PIX_PER_BLOCK;     // 1024 blocks
    perspective_warp_avg_kernel<<<grid, 256, 0, stream>>>(image, transforms, mask, out);
}

// Round 8
// 67.044 us; speedup vs baseline: 1.0802x; 1.0123x over previous
//
#include <hip/hip_runtime.h>
#include <hip/hip_bf16.h>

// PerspectiveTransformLayer: B=4, H=64, W=64, C=128, N=10 transforms.
// out[b,y,x,c] = sum_n mask[b,n,y,x] * warp_nearest(image[b], t[b,n])[y,x,c] / count
// count = sum_n mask[b,n,y,x] (0 if count==0).
//
// R8 = R7's LDS-deduplicated phase-1 + R4's wave shape (32 lanes/pixel).
// Rationale: with phase-1 deduped, per-wave VALU redundancy is gone, so the
// remaining term is L2-hit gather latency; R7 ran only 4 blocks/CU (4
// waves/SIMD). Going to 32 lanes/pixel doubles the grid (2048 blocks ->
// 8 blocks/CU, up to 8 waves/SIMD) for 2x latency-hiding capacity, while
// per-thread work drops to 10 single-float4 gathers (two half-batches of 5
// -> ~55-60 VGPR, occupancy not register-capped).
// Kept: XCD-bijective swizzle (2048%8==0), LDS transform table (exact pow2
// rescale), branch-free gathers, single 1/count normalize, NT stores.

namespace {

typedef float f32x4 __attribute__((ext_vector_type(4)));

constexpr int Bc = 4;
constexpr int Hc = 64;
constexpr int Wc = 64;
constexpr int Cc = 128;
constexpr int Nc = 10;
constexpr int C4 = Cc / 4;           // 32 float4 per pixel
constexpr int LANES_PER_PIX = 32;    // each lane owns 1 float4
constexpr int PIX_PER_BLOCK = 256 / LANES_PER_PIX;  // 8
constexpr int NXCD = 8;

__global__ __launch_bounds__(256)
void perspective_warp_avg_kernel(const float* __restrict__ image,
                                 const float* __restrict__ transforms,
                                 const float* __restrict__ mask,
                                 float* __restrict__ out) {
    // --- XCD-aware swizzle (bijective: gridDim.x = 2048 = 8*256) ---
    const int nblk = gridDim.x;                 // 2048
    const int chunk = nblk / NXCD;              // 256
    const int bid = (int)blockIdx.x;
    const int wg = (bid & (NXCD - 1)) * chunk + (bid >> 3);

    const int tid = threadIdx.x;
    const int pixel0 = wg * PIX_PER_BLOCK;      // 8 consecutive pixels; 8|4096
    const int b = pixel0 >> 12;                 // batch is uniform per block

    // Transforms for this batch -> LDS, pre-divided by perspective_mul.
    // mul = {1,1,4, 1,1,4, .25,.25}; /4 == *0.25f and /0.25 == *4.0f exactly.
    __shared__ float t_s[Nc * 8];
    if (tid < Nc * 8) {
        const int j = tid & 7;
        const float m = (j == 2 || j == 5) ? 0.25f : ((j >= 6) ? 4.0f : 1.0f);
        t_s[tid] = transforms[b * (Nc * 8) + tid] * m;
    }
    __syncthreads();

    // ---- Phase 1 (deduplicated): one thread per (pixel, transform) ----
    // pw[p][n] = { as_float(base_f4_offset), w, m, unused }
    __shared__ f32x4 pw[PIX_PER_BLOCK][Nc];
    if (tid < PIX_PER_BLOCK * Nc) {             // 80 threads
        const int p = tid / Nc;                 // 0..7 (magic-mul div)
        const int n = tid - p * Nc;             // 0..9
        const int pix = pixel0 + p;
        const int yx = pix & 4095;
        const float fy = (float)(yx >> 6);
        const float fx = (float)(yx & 63);

        const float t0 = t_s[n * 8 + 0];
        const float t1 = t_s[n * 8 + 1];
        const float t2 = t_s[n * 8 + 2];
        const float t3 = t_s[n * 8 + 3];
        const float t4 = t_s[n * 8 + 4];
        const float t5 = t_s[n * 8 + 5];
        const float t6 = t_s[n * 8 + 6];
        const float t7 = t_s[n * 8 + 7];

        const float denom = t6 * fx + t7 * fy + 1.0f;
        // exact f32 divides: these feed the floor(x+0.5) pixel decision
        const float xin = (t0 * fx + t1 * fy + t2) / denom;
        const float yin = (t3 * fx + t4 * fy + t5) / denom;

        const bool valid = (xin >= 0.0f) & (xin <= (float)(Wc - 1)) &
                           (yin >= 0.0f) & (yin <= (float)(Hc - 1));

        int xi = (int)floorf(xin + 0.5f);       // round half-up
        int yi = (int)floorf(yin + 0.5f);
        xi = min(max(xi, 0), Wc - 1);
        yi = min(max(yi, 0), Hc - 1);

        const float m = mask[(size_t)(b * Nc + n) * (Hc * Wc) + yx];
        const int base = (yi * Wc + xi) * C4;   // float4 offset, lane-invariant

        f32x4 rec;
        rec.x = __int_as_float(base);
        rec.y = valid ? m : 0.0f;               // w (image finite -> 0*s == 0)
        rec.z = m;                              // for count
        rec.w = 0.0f;
        pw[p][n] = rec;
    }
    __syncthreads();

    // ---- Phase 2: per-thread gathers (one float4 per pixel per transform) --
    const int pixInBlock = tid >> 5;            // 0..7
    const int c4 = tid & 31;                    // float4 slot within channels
    const int pixel = pixel0 + pixInBlock;

    const f32x4* __restrict__ imgb =
        (const f32x4*)(image) + (size_t)b * (Hc * Wc * C4);

    int   off[Nc];
    float w[Nc];
    float count = 0.f;
#pragma unroll
    for (int n = 0; n < Nc; ++n) {
        const f32x4 rec = pw[pixInBlock][n];    // broadcast read (same addr
        off[n] = __float_as_int(rec.x) + c4;    //  across the 32-lane group)
        w[n]   = rec.y;
        count += rec.z;
    }

    f32x4 acc = (f32x4)(0.f);
#pragma unroll
    for (int h = 0; h < 2; ++h) {
        f32x4 s[5];
#pragma unroll
        for (int k = 0; k < 5; ++k) s[k] = imgb[off[h * 5 + k]];
#pragma unroll
        for (int k = 0; k < 5; ++k) acc += w[h * 5 + k] * s[k];
    }

    // Final normalize: one exact divide, then multiply (<=1ulp vs per-elem
    // divide; no decision boundary downstream). count==0 -> acc==0 -> out 0.
    const float inv = (count > 0.f) ? (1.0f / count) : 0.0f;
    const f32x4 o = acc * inv;

    __builtin_nontemporal_store(o, ((f32x4*)out) + (size_t)pixel * C4 + c4);
}

}  // namespace

extern "C" void kernel_launch(void* const* d_in, const int* in_sizes, int n_in,
                              void* d_out, int out_size, void* d_ws, size_t ws_size,
                              hipStream_t stream) {
    const float* image      = (const float*)d_in[0];  // (4,64,64,128) f32
    const float* transforms = (const float*)d_in[1];  // (4,10,8) f32
    const float* mask       = (const float*)d_in[2];  // (4,10,64,64) f32
    float* out              = (float*)d_out;          // (4,64,64,128) f32

    const int totalPixels = Bc * Hc * Wc;             // 16384
    const int grid = totalPixels / PIX_PER_BLOCK;     // 2048 blocks
    perspective_warp_avg_kernel<<<grid, 256, 0, stream>>>(image, transforms, mask, out);
}